// Round 5
// baseline (3315.318 us; speedup 1.0000x reference)
//
#include <hip/hip_runtime.h>
#include <hip/hip_bf16.h>
#include <type_traits>

#define T_ 16384
#define H_ 2048
#define I_ 1024
#define E_ 8
#define K_ 2
#define R_ 16
#define P_ (T_*K_)   /* 32768 pairs */
#define BM 128
#define BK 32

typedef float  f32x4  __attribute__((ext_vector_type(4)));
typedef __bf16 bf16x4 __attribute__((ext_vector_type(4)));
typedef __bf16 bf16x8 __attribute__((ext_vector_type(8)));

// XOR swizzle: 8-element (16B) chunk index ^= (row>>1)&3  -> conflict-free frag reads/writes
__device__ __forceinline__ int swzc(int r, int c) {
  return (c & 7) | ((((c >> 3) ^ ((r >> 1) & 3)) & 3) << 3);
}

// fp32 -> (hi, lo) bf16 split; hi+lo captures ~16 mantissa bits (rel err ~2^-17)
__device__ __forceinline__ void cvt4(f32x4 v, bf16x4* h, bf16x4* l) {
#pragma unroll
  for (int j = 0; j < 4; ++j) {
    float f = v[j];
    __bf16 hh = (__bf16)f;
    (*h)[j] = hh;
    (*l)[j] = (__bf16)(f - (float)hh);
  }
}

__global__ __launch_bounds__(256) void zero_kernel(float* __restrict__ out, int* __restrict__ cnt) {
  size_t i = (size_t)blockIdx.x * 256 + threadIdx.x;
  f32x4 z = {0.f, 0.f, 0.f, 0.f};
  if (i < (size_t)T_ * H_ / 4) ((f32x4*)out)[i] = z;
  if (i < E_) cnt[i] = 0;
}

// generic fp32 -> bf16 hi/lo plane split
__global__ __launch_bounds__(256) void split_kernel(const float* __restrict__ src,
                                                    __bf16* __restrict__ dh,
                                                    __bf16* __restrict__ dl, long n4) {
  long i = (long)blockIdx.x * 256 + threadIdx.x;
  if (i < n4) {
    f32x4 v = ((const f32x4*)src)[i];
    bf16x4 h, l; cvt4(v, &h, &l);
    ((bf16x4*)dh)[i] = h;
    ((bf16x4*)dl)[i] = l;
  }
}

__global__ __launch_bounds__(256) void route_kernel(const int* __restrict__ ids,
                                                    const float* __restrict__ tw,
                                                    int* __restrict__ cnt,
                                                    int* __restrict__ tok,
                                                    float* __restrict__ wgt) {
  int s = blockIdx.x * 256 + threadIdx.x;
  if (s < P_) {
    int e = ids[s];
    int pos = atomicAdd(&cnt[e], 1);
    tok[e * P_ + pos] = s;
    wgt[e * P_ + pos] = tw[s];
  }
}

// U[s][r] = sum_h x[t][h] * a1[e][r][h]. Grouped: 16 pairs per wave amortize a1 reads.
__global__ __launch_bounds__(256) void lora_u_kernel(const float* __restrict__ x,
                                                     const float* __restrict__ a1,
                                                     const int* __restrict__ cnt,
                                                     const int* __restrict__ tok,
                                                     float* __restrict__ U) {
  const int e = blockIdx.y;
  const int n = cnt[e];
  const int i0 = blockIdx.x * 64;
  if (i0 >= n) return;
  const int w = threadIdx.x >> 6, lane = threadIdx.x & 63;
  const int r = lane >> 2, part = lane & 3;
  const int ib = i0 + w * 16;

  int sp[16];
  const float* xp[16];
#pragma unroll
  for (int p = 0; p < 16; ++p) {
    int ii = ib + p; if (ii >= n) ii = n - 1;
    sp[p] = tok[e * P_ + ii];
    xp[p] = x + (size_t)(sp[p] >> 1) * H_ + part * 4;
  }
  const float* ap = a1 + ((size_t)e * R_ + r) * H_ + part * 4;

  float acc[16];
#pragma unroll
  for (int p = 0; p < 16; ++p) acc[p] = 0.f;

  for (int h0 = 0; h0 < H_; h0 += 16) {
    f32x4 a4 = *(const f32x4*)(ap + h0);
#pragma unroll
    for (int p = 0; p < 16; ++p) {
      f32x4 xv = *(const f32x4*)(xp[p] + h0);
      acc[p] += xv[0]*a4[0] + xv[1]*a4[1] + xv[2]*a4[2] + xv[3]*a4[3];
    }
  }
#pragma unroll
  for (int p = 0; p < 16; ++p) {
    acc[p] += __shfl_xor(acc[p], 1);
    acc[p] += __shfl_xor(acc[p], 2);
    if (part == 0 && ib + p < n) U[(size_t)sp[p] * R_ + r] = acc[p];
  }
}

// V[s][r] = sum_i act[s][i] * a2[e][r][i]. Same grouped 16-pair batching.
__global__ __launch_bounds__(256) void lora_v_kernel(const __bf16* __restrict__ acth,
                                                     const __bf16* __restrict__ actl,
                                                     const float* __restrict__ a2,
                                                     const int* __restrict__ cnt,
                                                     const int* __restrict__ tok,
                                                     float* __restrict__ V) {
  const int e = blockIdx.y;
  const int n = cnt[e];
  const int i0 = blockIdx.x * 64;
  if (i0 >= n) return;
  const int w = threadIdx.x >> 6, lane = threadIdx.x & 63;
  const int r = lane >> 2, part = lane & 3;
  const int ib = i0 + w * 16;

  int sp[16];
#pragma unroll
  for (int p = 0; p < 16; ++p) {
    int ii = ib + p; if (ii >= n) ii = n - 1;
    sp[p] = tok[e * P_ + ii];
  }
  const float* ap = a2 + ((size_t)e * R_ + r) * I_ + part * 4;

  float acc[16];
#pragma unroll
  for (int p = 0; p < 16; ++p) acc[p] = 0.f;

  for (int i1 = 0; i1 < I_; i1 += 16) {
    f32x4 a4 = *(const f32x4*)(ap + i1);
#pragma unroll
    for (int p = 0; p < 16; ++p) {
      size_t off = (size_t)sp[p] * I_ + i1 + part * 4;
      bf16x4 hv = *(const bf16x4*)(acth + off);
      bf16x4 lv = *(const bf16x4*)(actl + off);
#pragma unroll
      for (int j = 0; j < 4; ++j) acc[p] += ((float)hv[j] + (float)lv[j]) * a4[j];
    }
  }
#pragma unroll
  for (int p = 0; p < 16; ++p) {
    acc[p] += __shfl_xor(acc[p], 1);
    acc[p] += __shfl_xor(acc[p], 2);
    if (part == 0 && ib + p < n) V[(size_t)sp[p] * R_ + r] = acc[p];
  }
}

struct S1g { bf16x8 ah[2], al[2], bh[2], bl[2]; };  // presplit regs
struct S0g { f32x4 a[4], b[4]; };                   // fp32-cvt regs

// GEMM1: act = silu(g)*u, g/u = x@w13^T (+ U@b1^T), split-bf16 3-pass MFMA.
// MODE=1: x/w13 pre-split bf16 planes (no cvt in loop). MODE=0: fp32+cvt fallback.
// Grid: (rowblk fast, colblk, e) -> weight panel L2-hot across consecutive blocks.
template<int MODE>
__global__ __launch_bounds__(256, 2) void gemm1_kernel(
    const float* __restrict__ x, const float* __restrict__ w13,
    const __bf16* __restrict__ xh, const __bf16* __restrict__ xl,
    const __bf16* __restrict__ w13h, const __bf16* __restrict__ w13l,
    const float* __restrict__ b1, const float* __restrict__ U,
    const int* __restrict__ cnt, const int* __restrict__ tok,
    __bf16* __restrict__ acth, __bf16* __restrict__ actl) {
  const int e = blockIdx.z;
  const int n = cnt[e];
  const int row0 = blockIdx.x * BM;
  if (row0 >= n) return;
  const int c0 = blockIdx.y * 64;

  __shared__ __bf16 lAh[2][BM*BK], lAl[2][BM*BK], lBh[2][BM*BK], lBl[2][BM*BK];
  __shared__ float sU[BM * R_];
  __shared__ int sTok[BM];

  const int tS = threadIdx.x;
  const int lane = tS & 63, wid = tS >> 6;
  const int wm = (wid & 1) * 64, wn = (wid >> 1) * 32;
  const int lr = lane & 15, lk = lane >> 4;

  // staging: thread = (row ar, col half c8): one row, 16 cols
  const int ar = tS >> 1;
  const int c8 = (tS & 1) * 16;
  const __bf16 *Ah_p = nullptr, *Al_p = nullptr, *Bh_p = nullptr, *Bl_p = nullptr;
  const float *Af_p = nullptr, *Bf_p = nullptr;
  {
    int i = row0 + ar; if (i >= n) i = n - 1;
    int s = tok[e * P_ + i];
    size_t axo = (size_t)(s >> 1) * H_ + c8;
    int bn = (ar < 64) ? (c0 + ar) : (I_ + c0 + (ar - 64));
    size_t bxo = ((size_t)e * (2 * I_) + bn) * H_ + c8;
    if constexpr (MODE) { Ah_p = xh + axo; Al_p = xl + axo; Bh_p = w13h + bxo; Bl_p = w13l + bxo; }
    else { Af_p = x + axo; Bf_p = w13 + bxo; }
  }

  f32x4 accg[4][2], accu[4][2];
  const f32x4 Z4 = {0.f, 0.f, 0.f, 0.f};
#pragma unroll
  for (int mf = 0; mf < 4; ++mf)
#pragma unroll
    for (int nf = 0; nf < 2; ++nf) { accg[mf][nf] = Z4; accu[mf][nf] = Z4; }

  int arow[4], brow[2];
#pragma unroll
  for (int mf = 0; mf < 4; ++mf) arow[mf] = wm + mf * 16 + lr;
#pragma unroll
  for (int nf = 0; nf < 2; ++nf) brow[nf] = wn + nf * 16 + lr;

  using SS = std::conditional_t<MODE != 0, S1g, S0g>;
  SS sA, sB;

  auto LD = [&](auto& rp, int kof) {
    if constexpr (MODE) {
#pragma unroll
      for (int j = 0; j < 2; ++j) {
        rp.ah[j] = *(const bf16x8*)(Ah_p + kof + j * 8);
        rp.al[j] = *(const bf16x8*)(Al_p + kof + j * 8);
        rp.bh[j] = *(const bf16x8*)(Bh_p + kof + j * 8);
        rp.bl[j] = *(const bf16x8*)(Bl_p + kof + j * 8);
      }
    } else {
#pragma unroll
      for (int j = 0; j < 4; ++j) {
        rp.a[j] = *(const f32x4*)(Af_p + kof + j * 4);
        rp.b[j] = *(const f32x4*)(Bf_p + kof + j * 4);
      }
    }
  };
  auto WR = [&](int buf, auto& rp) {
    if constexpr (MODE) {
#pragma unroll
      for (int j = 0; j < 2; ++j) {
        int sc = ar * BK + swzc(ar, c8 + j * 8);
        *(bf16x8*)&lAh[buf][sc] = rp.ah[j];
        *(bf16x8*)&lAl[buf][sc] = rp.al[j];
        *(bf16x8*)&lBh[buf][sc] = rp.bh[j];
        *(bf16x8*)&lBl[buf][sc] = rp.bl[j];
      }
    } else {
#pragma unroll
      for (int j = 0; j < 4; ++j) {
        int sc = ar * BK + swzc(ar, c8 + j * 4);
        bf16x4 h, l;
        cvt4(rp.a[j], &h, &l); *(bf16x4*)&lAh[buf][sc] = h; *(bf16x4*)&lAl[buf][sc] = l;
        cvt4(rp.b[j], &h, &l); *(bf16x4*)&lBh[buf][sc] = h; *(bf16x4*)&lBl[buf][sc] = l;
      }
    }
  };
  auto STEP = [&](int bs) {
    bf16x8 Ah[4], Al[4], Bh[4], Bl[4];  // B: [0..1]=gate, [2..3]=up
#pragma unroll
    for (int mf = 0; mf < 4; ++mf) {
      int rr = arow[mf]; int off = rr * BK + ((lk ^ ((rr >> 1) & 3)) << 3);
      Ah[mf] = *(const bf16x8*)&lAh[bs][off];
      Al[mf] = *(const bf16x8*)&lAl[bs][off];
    }
#pragma unroll
    for (int nf = 0; nf < 2; ++nf) {
      int rg = brow[nf]; int og = rg * BK + ((lk ^ ((rg >> 1) & 3)) << 3);
      Bh[nf] = *(const bf16x8*)&lBh[bs][og];
      Bl[nf] = *(const bf16x8*)&lBl[bs][og];
      int ru = 64 + rg; int ou = ru * BK + ((lk ^ ((ru >> 1) & 3)) << 3);
      Bh[2 + nf] = *(const bf16x8*)&lBh[bs][ou];
      Bl[2 + nf] = *(const bf16x8*)&lBl[bs][ou];
    }
#pragma unroll
    for (int mf = 0; mf < 4; ++mf)
#pragma unroll
      for (int nf = 0; nf < 2; ++nf) {
        accg[mf][nf] = __builtin_amdgcn_mfma_f32_16x16x32_bf16(Ah[mf], Bh[nf], accg[mf][nf], 0, 0, 0);
        accg[mf][nf] = __builtin_amdgcn_mfma_f32_16x16x32_bf16(Ah[mf], Bl[nf], accg[mf][nf], 0, 0, 0);
        accg[mf][nf] = __builtin_amdgcn_mfma_f32_16x16x32_bf16(Al[mf], Bh[nf], accg[mf][nf], 0, 0, 0);
        accu[mf][nf] = __builtin_amdgcn_mfma_f32_16x16x32_bf16(Ah[mf], Bh[2+nf], accu[mf][nf], 0, 0, 0);
        accu[mf][nf] = __builtin_amdgcn_mfma_f32_16x16x32_bf16(Ah[mf], Bl[2+nf], accu[mf][nf], 0, 0, 0);
        accu[mf][nf] = __builtin_amdgcn_mfma_f32_16x16x32_bf16(Al[mf], Bh[2+nf], accu[mf][nf], 0, 0, 0);
      }
  };

  const int NK = H_ / BK;  // 64 (even)
  LD(sA, 0); WR(0, sA); LD(sB, BK);
  __syncthreads();
  for (int kt = 0; kt < NK; kt += 2) {
    if (kt + 2 < NK) LD(sA, (kt + 2) * BK);
    STEP(0);
    WR(1, sB);
    __syncthreads();
    if (kt + 3 < NK) LD(sB, (kt + 3) * BK);
    STEP(1);
    if (kt + 2 < NK) WR(0, sA);
    __syncthreads();
  }

  // epilogue: stage U rows + tokens
  if (tS < BM) {
    int i = row0 + tS; if (i >= n) i = n - 1;
    sTok[tS] = tok[e * P_ + i];
  }
  {
    int r2 = tS >> 1, hf = (tS & 1) * 8;
    int i = row0 + r2; if (i >= n) i = n - 1;
    int s = tok[e * P_ + i];
    *(f32x4*)&sU[r2 * R_ + hf]     = *(const f32x4*)&U[(size_t)s * R_ + hf];
    *(f32x4*)&sU[r2 * R_ + hf + 4] = *(const f32x4*)&U[(size_t)s * R_ + hf + 4];
  }
  __syncthreads();

#pragma unroll
  for (int nf = 0; nf < 2; ++nf) {
    int colg = c0 + wn + nf * 16 + lr;
    const float* bg = b1 + ((size_t)e * (2 * I_) + colg) * R_;
    const float* bu = b1 + ((size_t)e * (2 * I_) + I_ + colg) * R_;
    float bgr[R_], bur[R_];
#pragma unroll
    for (int rr = 0; rr < R_; rr += 4) {
      *(f32x4*)&bgr[rr] = *(const f32x4*)(bg + rr);
      *(f32x4*)&bur[rr] = *(const f32x4*)(bu + rr);
    }
#pragma unroll
    for (int mf = 0; mf < 4; ++mf)
#pragma unroll
      for (int j = 0; j < 4; ++j) {
        int trow = wm + mf * 16 + lk * 4 + j;
        float g = accg[mf][nf][j], u = accu[mf][nf][j];
        float ag = 0.f, au = 0.f;
#pragma unroll
        for (int rr = 0; rr < R_; ++rr) { float uv = sU[trow * R_ + rr]; ag += uv * bgr[rr]; au += uv * bur[rr]; }
        g += ag; u += au;
        float a = g / (1.f + __expf(-g)) * u;
        int i = row0 + trow;
        if (i < n) {
          int s = sTok[trow];
          __bf16 hi = (__bf16)a; float hff = (float)hi; __bf16 lo = (__bf16)(a - hff);
          acth[(size_t)s * I_ + colg] = hi;
          actl[(size_t)s * I_ + colg] = lo;
        }
      }
  }
}

struct S2_1 { bf16x8 ah[2], al[2], bh[2], bl[2]; };
struct S2_0 { bf16x8 ah[2], al[2]; f32x4 b[4]; };

// GEMM2: out[t] += w * (act@w2^T + V@b2^T). A (act) always bf16 planes; B per MODE.
template<int MODE>
__global__ __launch_bounds__(256, 2) void gemm2_kernel(
    const float* __restrict__ w2,
    const __bf16* __restrict__ w2h, const __bf16* __restrict__ w2l,
    const float* __restrict__ b2,
    const __bf16* __restrict__ acth, const __bf16* __restrict__ actl,
    const float* __restrict__ V, const int* __restrict__ cnt,
    const int* __restrict__ tok, const float* __restrict__ wgt,
    float* __restrict__ out) {
  const int e = blockIdx.z;
  const int n = cnt[e];
  const int row0 = blockIdx.x * BM;
  if (row0 >= n) return;
  const int cb0 = blockIdx.y * 128;

  __shared__ __bf16 lAh[2][BM*BK], lAl[2][BM*BK], lBh[2][BM*BK], lBl[2][BM*BK];
  __shared__ float sV[BM * R_];
  __shared__ float sW[BM];
  __shared__ int sTok[BM];

  const int tS = threadIdx.x;
  const int lane = tS & 63, wid = tS >> 6;
  const int wm = (wid & 1) * 64, wn = (wid >> 1) * 64;
  const int lr = lane & 15, lk = lane >> 4;

  const int ar = tS >> 1;
  const int c8 = (tS & 1) * 16;
  const __bf16 *ah_p, *al_p;
  const __bf16 *Bh_p = nullptr, *Bl_p = nullptr;
  const float *Bf_p = nullptr;
  {
    int i = row0 + ar; if (i >= n) i = n - 1;
    int s = tok[e * P_ + i];
    ah_p = acth + (size_t)s * I_ + c8;
    al_p = actl + (size_t)s * I_ + c8;
    size_t bxo = ((size_t)e * H_ + cb0 + ar) * I_ + c8;
    if constexpr (MODE) { Bh_p = w2h + bxo; Bl_p = w2l + bxo; }
    else { Bf_p = w2 + bxo; }
  }

  f32x4 acc[4][4];
  const f32x4 Z4 = {0.f, 0.f, 0.f, 0.f};
#pragma unroll
  for (int mf = 0; mf < 4; ++mf)
#pragma unroll
    for (int nf = 0; nf < 4; ++nf) acc[mf][nf] = Z4;

  int arow[4], brow[4];
#pragma unroll
  for (int mf = 0; mf < 4; ++mf) arow[mf] = wm + mf * 16 + lr;
#pragma unroll
  for (int nf = 0; nf < 4; ++nf) brow[nf] = wn + nf * 16 + lr;

  using SS = std::conditional_t<MODE != 0, S2_1, S2_0>;
  SS sA, sB;

  auto LD = [&](auto& rp, int kof) {
#pragma unroll
    for (int j = 0; j < 2; ++j) {
      rp.ah[j] = *(const bf16x8*)(ah_p + kof + j * 8);
      rp.al[j] = *(const bf16x8*)(al_p + kof + j * 8);
    }
    if constexpr (MODE) {
#pragma unroll
      for (int j = 0; j < 2; ++j) {
        rp.bh[j] = *(const bf16x8*)(Bh_p + kof + j * 8);
        rp.bl[j] = *(const bf16x8*)(Bl_p + kof + j * 8);
      }
    } else {
#pragma unroll
      for (int j = 0; j < 4; ++j) rp.b[j] = *(const f32x4*)(Bf_p + kof + j * 4);
    }
  };
  auto WR = [&](int buf, auto& rp) {
#pragma unroll
    for (int j = 0; j < 2; ++j) {
      int sc = ar * BK + swzc(ar, c8 + j * 8);
      *(bf16x8*)&lAh[buf][sc] = rp.ah[j];
      *(bf16x8*)&lAl[buf][sc] = rp.al[j];
    }
    if constexpr (MODE) {
#pragma unroll
      for (int j = 0; j < 2; ++j) {
        int sc = ar * BK + swzc(ar, c8 + j * 8);
        *(bf16x8*)&lBh[buf][sc] = rp.bh[j];
        *(bf16x8*)&lBl[buf][sc] = rp.bl[j];
      }
    } else {
#pragma unroll
      for (int j = 0; j < 4; ++j) {
        int sc = ar * BK + swzc(ar, c8 + j * 4);
        bf16x4 h, l; cvt4(rp.b[j], &h, &l);
        *(bf16x4*)&lBh[buf][sc] = h; *(bf16x4*)&lBl[buf][sc] = l;
      }
    }
  };
  auto STEP = [&](int bs) {
    bf16x8 Ah[4], Al[4];
#pragma unroll
    for (int mf = 0; mf < 4; ++mf) {
      int rr = arow[mf]; int off = rr * BK + ((lk ^ ((rr >> 1) & 3)) << 3);
      Ah[mf] = *(const bf16x8*)&lAh[bs][off];
      Al[mf] = *(const bf16x8*)&lAl[bs][off];
    }
#pragma unroll
    for (int nf = 0; nf < 4; ++nf) {
      int rr = brow[nf]; int off = rr * BK + ((lk ^ ((rr >> 1) & 3)) << 3);
      bf16x8 Bh = *(const bf16x8*)&lBh[bs][off];
      bf16x8 Bl = *(const bf16x8*)&lBl[bs][off];
#pragma unroll
      for (int mf = 0; mf < 4; ++mf) {
        acc[mf][nf] = __builtin_amdgcn_mfma_f32_16x16x32_bf16(Ah[mf], Bh, acc[mf][nf], 0, 0, 0);
        acc[mf][nf] = __builtin_amdgcn_mfma_f32_16x16x32_bf16(Ah[mf], Bl, acc[mf][nf], 0, 0, 0);
        acc[mf][nf] = __builtin_amdgcn_mfma_f32_16x16x32_bf16(Al[mf], Bh, acc[mf][nf], 0, 0, 0);
      }
    }
  };

  const int NK = I_ / BK;  // 32 (even)
  LD(sA, 0); WR(0, sA); LD(sB, BK);
  __syncthreads();
  for (int kt = 0; kt < NK; kt += 2) {
    if (kt + 2 < NK) LD(sA, (kt + 2) * BK);
    STEP(0);
    WR(1, sB);
    __syncthreads();
    if (kt + 3 < NK) LD(sB, (kt + 3) * BK);
    STEP(1);
    if (kt + 2 < NK) WR(0, sA);
    __syncthreads();
  }

  if (tS < BM) {
    int i = row0 + tS;
    sW[tS] = (i < n) ? wgt[e * P_ + i] : 0.f;
    int ii = (i < n) ? i : (n - 1);
    sTok[tS] = tok[e * P_ + ii];
  }
  {
    int r2 = tS >> 1, hf = (tS & 1) * 8;
    int i = row0 + r2; if (i >= n) i = n - 1;
    int s = tok[e * P_ + i];
    *(f32x4*)&sV[r2 * R_ + hf]     = *(const f32x4*)&V[(size_t)s * R_ + hf];
    *(f32x4*)&sV[r2 * R_ + hf + 4] = *(const f32x4*)&V[(size_t)s * R_ + hf + 4];
  }
  __syncthreads();

#pragma unroll
  for (int nf = 0; nf < 4; ++nf) {
    int col = cb0 + wn + nf * 16 + lr;
    const float* b2p = b2 + ((size_t)e * H_ + col) * R_;
    float br_[R_];
#pragma unroll
    for (int rr = 0; rr < R_; rr += 4) *(f32x4*)&br_[rr] = *(const f32x4*)(b2p + rr);
#pragma unroll
    for (int mf = 0; mf < 4; ++mf)
#pragma unroll
      for (int j = 0; j < 4; ++j) {
        int trow = wm + mf * 16 + lk * 4 + j;
        int i = row0 + trow;
        if (i < n) {
          float y = acc[mf][nf][j];
#pragma unroll
          for (int rr = 0; rr < R_; ++rr) y += sV[trow * R_ + rr] * br_[rr];
          unsafeAtomicAdd(&out[(size_t)(sTok[trow] >> 1) * H_ + col], sW[trow] * y);
        }
      }
  }
}

extern "C" void kernel_launch(void* const* d_in, const int* in_sizes, int n_in,
                              void* d_out, int out_size, void* d_ws, size_t ws_size,
                              hipStream_t stream) {
  const float* x   = (const float*)d_in[0];
  const float* tw  = (const float*)d_in[1];
  const int*   ids = (const int*)d_in[2];
  const float* w13 = (const float*)d_in[3];
  const float* w2  = (const float*)d_in[4];
  const float* a1  = (const float*)d_in[5];
  const float* b1  = (const float*)d_in[6];
  const float* a2  = (const float*)d_in[7];
  const float* b2  = (const float*)d_in[8];
  float* out = (float*)d_out;

  char* ws = (char*)d_ws;
  size_t o = 0;
  auto alloc = [&](size_t bytes) { size_t p = o; o = (o + bytes + 255) & ~(size_t)255; return p; };
  size_t o_cnt = alloc(256);
  size_t o_tok = alloc((size_t)E_ * P_ * 4);
  size_t o_wgt = alloc((size_t)E_ * P_ * 4);
  size_t o_U   = alloc((size_t)P_ * R_ * 4);
  size_t o_V   = alloc((size_t)P_ * R_ * 4);
  size_t o_ah  = alloc((size_t)P_ * I_ * 2);
  size_t o_al  = alloc((size_t)P_ * I_ * 2);
  size_t need_base = o;
  size_t o_xh  = alloc((size_t)T_ * H_ * 2);
  size_t o_xl  = alloc((size_t)T_ * H_ * 2);
  size_t o_wh  = alloc((size_t)E_ * 2 * I_ * H_ * 2);
  size_t o_wl  = alloc((size_t)E_ * 2 * I_ * H_ * 2);
  size_t o_2h  = alloc((size_t)E_ * H_ * I_ * 2);
  size_t o_2l  = alloc((size_t)E_ * H_ * I_ * 2);
  size_t need_split = o;

  if (ws_size < need_base) return;  // insufficient scratch: fail cleanly
  const bool use_split = (ws_size >= need_split);

  int* cnt   = (int*)(ws + o_cnt);
  int* tok   = (int*)(ws + o_tok);
  float* wgt = (float*)(ws + o_wgt);
  float* U   = (float*)(ws + o_U);
  float* V   = (float*)(ws + o_V);
  __bf16* acth = (__bf16*)(ws + o_ah);
  __bf16* actl = (__bf16*)(ws + o_al);
  __bf16* xh = (__bf16*)(ws + o_xh),  *xl = (__bf16*)(ws + o_xl);
  __bf16* wh = (__bf16*)(ws + o_wh),  *wl = (__bf16*)(ws + o_wl);
  __bf16* w2h = (__bf16*)(ws + o_2h), *w2l = (__bf16*)(ws + o_2l);

  zero_kernel<<<(T_ * H_ / 4 + 255) / 256, 256, 0, stream>>>(out, cnt);
  route_kernel<<<P_ / 256, 256, 0, stream>>>(ids, tw, cnt, tok, wgt);
  if (use_split) {
    long nx = (long)T_ * H_ / 4, nw = (long)E_ * 2 * I_ * H_ / 4, n2 = (long)E_ * H_ * I_ / 4;
    split_kernel<<<(nx + 255) / 256, 256, 0, stream>>>(x, xh, xl, nx);
    split_kernel<<<(nw + 255) / 256, 256, 0, stream>>>(w13, wh, wl, nw);
    split_kernel<<<(n2 + 255) / 256, 256, 0, stream>>>(w2, w2h, w2l, n2);
  }
  lora_u_kernel<<<dim3(P_ / 64, E_), 256, 0, stream>>>(x, a1, cnt, tok, U);
  if (use_split) {
    gemm1_kernel<1><<<dim3(P_ / BM, I_ / 64, E_), 256, 0, stream>>>(
        x, w13, xh, xl, wh, wl, b1, U, cnt, tok, acth, actl);
  } else {
    gemm1_kernel<0><<<dim3(P_ / BM, I_ / 64, E_), 256, 0, stream>>>(
        x, w13, nullptr, nullptr, nullptr, nullptr, b1, U, cnt, tok, acth, actl);
  }
  lora_v_kernel<<<dim3(P_ / 64, E_), 256, 0, stream>>>(acth, actl, a2, cnt, tok, V);
  if (use_split) {
    gemm2_kernel<1><<<dim3(P_ / BM, H_ / 128, E_), 256, 0, stream>>>(
        w2, w2h, w2l, b2, acth, actl, V, cnt, tok, wgt, out);
  } else {
    gemm2_kernel<0><<<dim3(P_ / BM, H_ / 128, E_), 256, 0, stream>>>(
        w2, nullptr, nullptr, b2, acth, actl, V, cnt, tok, wgt, out);
  }
}